// Round 2
// baseline (303.406 us; speedup 1.0000x reference)
//
#include <hip/hip_runtime.h>

#define NE 8
#define NH 1024
#define NI 1024
#define NGU 2048
#define MTOK 2048
#define TSLOT 4096
#define MAXTILES 80
#define BM 64
#define BK 32

typedef short s16x8 __attribute__((ext_vector_type(8)));
typedef float f32x4 __attribute__((ext_vector_type(4)));

// ---- ws layout (bytes) ----
#define WS_SEG   0         // 16 ints
#define WS_DESC  64        // 80 ints
#define WS_SLOT  1024      // 4096 ints
#define WS_INTER 65536     // bf16 [4096][1024] = 8388608 B

__device__ inline unsigned short f2bf(float f) {
    unsigned u = __builtin_bit_cast(unsigned, f);
    u += 0x7fffu + ((u >> 16) & 1u);   // round-to-nearest-even
    return (unsigned short)(u >> 16);
}

// ---------------- kernel 1: expert-sort + tile descriptors ----------------
__global__ void k_build(const int* __restrict__ ridx, int* __restrict__ seg,
                        int* __restrict__ desc, int* __restrict__ slot_of) {
    __shared__ int cnt[NE];
    __shared__ int cur[NE];
    int tid = threadIdx.x;
    if (tid < NE) cnt[tid] = 0;
    __syncthreads();
    for (int s = tid; s < TSLOT; s += blockDim.x) atomicAdd(&cnt[ridx[s] & 7], 1);
    __syncthreads();
    if (tid == 0) {
        int a = 0;
        for (int e = 0; e < NE; ++e) { seg[e] = a; cur[e] = a; a += cnt[e]; }
        seg[NE] = a;
        int nt = 0;
        for (int e = 0; e < NE; ++e)
            for (int m0 = 0; m0 < cnt[e]; m0 += BM) desc[nt++] = (e << 16) | (m0 / BM);
        for (; nt < MAXTILES; ++nt) desc[nt] = -1;
    }
    __syncthreads();
    for (int s = tid; s < TSLOT; s += blockDim.x) {
        int e = ridx[s] & 7;
        int p = atomicAdd(&cur[e], 1);
        slot_of[p] = s;
    }
}

// ---------------- kernel 2: gate_up GEMM + bias + SwiGLU ----------------
__global__ __launch_bounds__(256) void k_gateup(
        const float* __restrict__ x,    // [MTOK][NH] fp32
        const float* __restrict__ w,    // [NE][NH][NGU] fp32
        const float* __restrict__ bias, // [NE][NGU] fp32
        const int* __restrict__ seg, const int* __restrict__ desc,
        const int* __restrict__ slot_of,
        unsigned short* __restrict__ inter) {    // [TSLOT][NI] bf16 bits
    int d = desc[blockIdx.x];
    if (d < 0) return;
    int e = d >> 16, mt = d & 0xffff;
    int seg0 = seg[e];
    int Te = seg[e + 1] - seg0;
    int m0 = mt * BM;

    __shared__ unsigned short As[BM * 40];  // padded stride 40
    __shared__ int tok[BM];

    int tid = threadIdx.x;
    if (tid < BM) {
        int m = m0 + tid;
        tok[tid] = (m < Te) ? (slot_of[seg0 + m] >> 1) : -1;
    }
    __syncthreads();

    int lane = tid & 63, wave = tid >> 6;
    int arow = tid >> 2, acol = (tid & 3) * 8;
    int ta = tok[arow];
    int kq = lane >> 4, ml = lane & 15;
    int nb = blockIdx.y * 128 + wave * 32;
    const float* wp = w + (size_t)e * NH * NGU;

    f32x4 zero = {0.f, 0.f, 0.f, 0.f};
    f32x4 acc[4][2];
#pragma unroll
    for (int i = 0; i < 4; ++i) { acc[i][0] = zero; acc[i][1] = zero; }

    for (int kb = 0; kb < NH; kb += BK) {
        float4 a0 = {0.f,0.f,0.f,0.f}, a1 = {0.f,0.f,0.f,0.f};
        if (ta >= 0) {
            const float* xp = x + (size_t)ta * NH + kb + acol;
            a0 = *(const float4*)xp;
            a1 = *(const float4*)(xp + 4);
        }
        s16x8 av;
        av[0] = (short)f2bf(a0.x); av[1] = (short)f2bf(a0.y);
        av[2] = (short)f2bf(a0.z); av[3] = (short)f2bf(a0.w);
        av[4] = (short)f2bf(a1.x); av[5] = (short)f2bf(a1.y);
        av[6] = (short)f2bf(a1.z); av[7] = (short)f2bf(a1.w);
        __syncthreads();
        *(s16x8*)&As[arow * 40 + acol] = av;
        __syncthreads();

        s16x8 afr[4];
#pragma unroll
        for (int msi = 0; msi < 4; ++msi)
            afr[msi] = *(const s16x8*)&As[(msi * 16 + ml) * 40 + kq * 8];

        s16x8 bfr[2];
#pragma unroll
        for (int s = 0; s < 2; ++s) {
            const float* bp = wp + (size_t)(kb + kq * 8) * NGU + nb + s * 16 + ml;
#pragma unroll
            for (int j = 0; j < 8; ++j) bfr[s][j] = (short)f2bf(bp[(size_t)j * NGU]);
        }
#pragma unroll
        for (int msi = 0; msi < 4; ++msi)
#pragma unroll
            for (int s = 0; s < 2; ++s)
                acc[msi][s] = __builtin_amdgcn_mfma_f32_16x16x32_bf16(
                    afr[msi], bfr[s], acc[msi][s], 0, 0, 0);
    }

    // epilogue: +bias, pair even/odd cols via shfl, SwiGLU, store bf16 inter
#pragma unroll
    for (int s = 0; s < 2; ++s) {
        int n = nb + s * 16 + ml;
        float bv = bias[e * NGU + n];
#pragma unroll
        for (int msi = 0; msi < 4; ++msi) {
#pragma unroll
            for (int r = 0; r < 4; ++r) {
                float v = acc[msi][s][r] + bv;
                float pr = __shfl_xor(v, 1, 64);
                float g = (lane & 1) ? pr : v;   // even column = gate
                float u = (lane & 1) ? v : pr;   // odd column  = up
                g = fminf(g, 7.0f);
                u = fminf(fmaxf(u, -7.0f), 7.0f);
                float glu = g / (1.0f + __expf(-1.702f * g));
                float y = (u + 1.0f) * glu;
                int mrow = m0 + msi * 16 + kq * 4 + r;
                if (!(lane & 1) && mrow < Te)
                    inter[(size_t)(seg0 + mrow) * NI + (n >> 1)] = f2bf(y);
            }
        }
    }
}

// ---------------- kernel 3: down GEMM + bias + weight + scatter-add ----------------
__global__ __launch_bounds__(256) void k_down(
        const unsigned short* __restrict__ inter, // [TSLOT][NI] bf16
        const float* __restrict__ w,     // [NE][NI][NH] fp32
        const float* __restrict__ bias,  // [NE][NH] fp32
        const float* __restrict__ rw,    // [MTOK][NE] fp32
        const int* __restrict__ seg, const int* __restrict__ desc,
        const int* __restrict__ slot_of,
        float* __restrict__ out) {       // [MTOK][NH] fp32 (pre-zeroed)
    int d = desc[blockIdx.x];
    if (d < 0) return;
    int e = d >> 16, mt = d & 0xffff;
    int seg0 = seg[e];
    int Te = seg[e + 1] - seg0;
    int m0 = mt * BM;

    __shared__ unsigned short As[BM * 40];

    int tid = threadIdx.x;
    int lane = tid & 63, wave = tid >> 6;
    int arow = tid >> 2, acol = (tid & 3) * 8;
    bool avalid = (m0 + arow) < Te;
    int kq = lane >> 4, ml = lane & 15;
    int nb = blockIdx.y * 128 + wave * 32;
    const float* wp = w + (size_t)e * NI * NH;

    f32x4 zero = {0.f, 0.f, 0.f, 0.f};
    f32x4 acc[4][2];
#pragma unroll
    for (int i = 0; i < 4; ++i) { acc[i][0] = zero; acc[i][1] = zero; }

    for (int kb = 0; kb < NI; kb += BK) {
        s16x8 av = {0, 0, 0, 0, 0, 0, 0, 0};
        if (avalid) av = *(const s16x8*)(inter + (size_t)(seg0 + m0 + arow) * NI + kb + acol);
        __syncthreads();
        *(s16x8*)&As[arow * 40 + acol] = av;
        __syncthreads();

        s16x8 afr[4];
#pragma unroll
        for (int msi = 0; msi < 4; ++msi)
            afr[msi] = *(const s16x8*)&As[(msi * 16 + ml) * 40 + kq * 8];

        s16x8 bfr[2];
#pragma unroll
        for (int s = 0; s < 2; ++s) {
            const float* bp = wp + (size_t)(kb + kq * 8) * NH + nb + s * 16 + ml;
#pragma unroll
            for (int j = 0; j < 8; ++j) bfr[s][j] = (short)f2bf(bp[(size_t)j * NH]);
        }
#pragma unroll
        for (int msi = 0; msi < 4; ++msi)
#pragma unroll
            for (int s = 0; s < 2; ++s)
                acc[msi][s] = __builtin_amdgcn_mfma_f32_16x16x32_bf16(
                    afr[msi], bfr[s], acc[msi][s], 0, 0, 0);
    }

    float bv[2];
    bv[0] = bias[e * NH + nb + ml];
    bv[1] = bias[e * NH + nb + 16 + ml];

#pragma unroll
    for (int msi = 0; msi < 4; ++msi) {
#pragma unroll
        for (int r = 0; r < 4; ++r) {
            int mrow = m0 + msi * 16 + kq * 4 + r;
            if (mrow < Te) {
                int slot = slot_of[seg0 + mrow];
                int token = slot >> 1;
                float wgt = rw[token * NE + e];
#pragma unroll
                for (int s = 0; s < 2; ++s) {
                    int n = nb + s * 16 + ml;
                    float v = (acc[msi][s][r] + bv[s]) * wgt;
                    atomicAdd(&out[(size_t)token * NH + n], v);
                }
            }
        }
    }
}

extern "C" void kernel_launch(void* const* d_in, const int* in_sizes, int n_in,
                              void* d_out, int out_size, void* d_ws, size_t ws_size,
                              hipStream_t stream) {
    const float* x   = (const float*)d_in[0];
    const int*   ri  = (const int*)d_in[1];
    const float* rw  = (const float*)d_in[2];
    const float* wgu = (const float*)d_in[3];
    const float* bgu = (const float*)d_in[4];
    const float* wd  = (const float*)d_in[5];
    const float* bd  = (const float*)d_in[6];
    float* out = (float*)d_out;

    char* ws = (char*)d_ws;
    int* seg      = (int*)(ws + WS_SEG);
    int* desc     = (int*)(ws + WS_DESC);
    int* slot_of  = (int*)(ws + WS_SLOT);
    unsigned short* inter = (unsigned short*)(ws + WS_INTER);

    hipMemsetAsync(out, 0, (size_t)MTOK * NH * sizeof(float), stream);
    hipLaunchKernelGGL(k_build, dim3(1), dim3(256), 0, stream, ri, seg, desc, slot_of);
    hipLaunchKernelGGL(k_gateup, dim3(MAXTILES, NGU / 128), dim3(256), 0, stream,
                       x, wgu, bgu, seg, desc, slot_of, inter);
    hipLaunchKernelGGL(k_down, dim3(MAXTILES, NH / 128), dim3(256), 0, stream,
                       inter, wd, bd, rw, seg, desc, slot_of, out);
}

// Round 3
// 272.741 us; speedup vs baseline: 1.1124x; 1.1124x over previous
//
#include <hip/hip_runtime.h>

#define NE 8
#define NH 1024
#define NI 1024
#define NGU 2048
#define MTOK 2048
#define TSLOT 4096

#define MAXT64 80     // slow path: 64-row tiles
#define MAXT128 40    // fast path: 128-row tiles

typedef short s16x8 __attribute__((ext_vector_type(8)));
typedef float f32x4 __attribute__((ext_vector_type(4)));
typedef unsigned short u16;

// ---- ws layout (bytes) ----
#define WS_SEG      0
#define WS_DESC64   64
#define WS_DESC128  384
#define WS_SLOT     1024
#define WS_INTER    32768
#define INTER_ROWS  4224                    // 4096 + 128 pad rows (down-tile overrun)
#define WS_WTGU     8683520UL               // 32768 + 4224*1024*2
#define WS_WTD      42237952UL              // + 8*2048*1024*2
#define WS_NEED_FAST 59015168UL             // + 8*1024*1024*2

__device__ inline u16 f2bf(float f) {
    unsigned u = __builtin_bit_cast(unsigned, f);
    u += 0x7fffu + ((u >> 16) & 1u);
    return (u16)(u >> 16);
}

__device__ inline void lds_dma16(const u16* g, u16* l) {
    __builtin_amdgcn_global_load_lds(
        (const __attribute__((address_space(1))) unsigned int*)g,
        (__attribute__((address_space(3))) unsigned int*)l, 16, 0, 0);
}

// swizzled LDS byte offset: row-stride 128B (64 bf16), 16B blocks XORed by row&7
__device__ inline int lds_off(int row, int blk) {
    return (row << 7) | (((blk ^ (row & 7)) & 7) << 4);
}

// ---------------- kernel 1: expert-sort + tile descriptors ----------------
__global__ void k_build(const int* __restrict__ ridx, int* __restrict__ seg,
                        int* __restrict__ d64, int* __restrict__ d128,
                        int* __restrict__ slot_of) {
    __shared__ int cnt[NE];
    __shared__ int cur[NE];
    int tid = threadIdx.x;
    if (tid < NE) cnt[tid] = 0;
    __syncthreads();
    for (int s = tid; s < TSLOT; s += blockDim.x) atomicAdd(&cnt[ridx[s] & 7], 1);
    __syncthreads();
    if (tid == 0) {
        int a = 0;
        for (int e = 0; e < NE; ++e) { seg[e] = a; cur[e] = a; a += cnt[e]; }
        seg[NE] = a;
        int nt = 0;
        for (int e = 0; e < NE; ++e)
            for (int m0 = 0; m0 < cnt[e]; m0 += 64) d64[nt++] = (e << 16) | (m0 / 64);
        for (; nt < MAXT64; ++nt) d64[nt] = -1;
        nt = 0;
        for (int e = 0; e < NE; ++e)
            for (int m0 = 0; m0 < cnt[e]; m0 += 128) d128[nt++] = (e << 16) | (m0 / 128);
        for (; nt < MAXT128; ++nt) d128[nt] = -1;
    }
    __syncthreads();
    for (int s = tid; s < TSLOT; s += blockDim.x) {
        int e = ridx[s] & 7;
        int p = atomicAdd(&cur[e], 1);
        slot_of[p] = s;
    }
}

// ---------------- transpose+convert: W[e][K][N] fp32 -> WT[e][N][K] bf16 ----------------
__global__ __launch_bounds__(256) void k_tr(const float* __restrict__ W,
                                            u16* __restrict__ WT, int K, int N) {
    __shared__ u16 T[64][72];   // row stride 144B (16B-aligned), breaks pow2 banks
    int tid = threadIdx.x;
    const float* in = W + (size_t)blockIdx.z * K * N;
    u16* out = WT + (size_t)blockIdx.z * N * K;
    int n0 = blockIdx.x * 64, k0 = blockIdx.y * 64;
#pragma unroll
    for (int p = 0; p < 4; ++p) {
        int idx = p * 256 + tid;
        int kr = idx >> 4, nc = (idx & 15) * 4;
        float4 v = *(const float4*)(in + (size_t)(k0 + kr) * N + n0 + nc);
        T[nc + 0][kr] = f2bf(v.x); T[nc + 1][kr] = f2bf(v.y);
        T[nc + 2][kr] = f2bf(v.z); T[nc + 3][kr] = f2bf(v.w);
    }
    __syncthreads();
#pragma unroll
    for (int p = 0; p < 2; ++p) {
        int idx = p * 256 + tid;
        int nr = idx >> 3, kc = (idx & 7) * 8;
        s16x8 vv = *(const s16x8*)&T[nr][kc];
        *(s16x8*)(out + (size_t)(n0 + nr) * K + k0 + kc) = vv;
    }
}

// ---------------- fast kernel: gate_up GEMM + bias + SwiGLU ----------------
__global__ __launch_bounds__(256) void k_gateup_f(
        const float* __restrict__ x,     // [MTOK][NH] fp32
        const u16* __restrict__ wt,      // [NE][NGU][NH] bf16 (n-major)
        const float* __restrict__ bias,  // [NE][NGU]
        const int* __restrict__ seg, const int* __restrict__ desc,
        const int* __restrict__ slot_of,
        u16* __restrict__ inter) {       // [INTER_ROWS][NI] bf16
    int d = desc[blockIdx.x];
    if (d < 0) return;
    int e = d >> 16, mt = d & 0xffff;
    int seg0 = seg[e], Te = seg[e + 1] - seg0, m0 = mt * 128;

    __shared__ __align__(16) u16 As[128 * 64];
    __shared__ __align__(16) u16 Bs[128 * 64];
    __shared__ int tok[128];

    int tid = threadIdx.x;
    if (tid < 128) {
        int m = m0 + tid;
        tok[tid] = (m < Te) ? (slot_of[seg0 + m] >> 1) : -1;
    }
    int lane = tid & 63, w = tid >> 6;
    int ml = lane & 15, kq = lane >> 4;
    int wm = w >> 1, wn = w & 1;
    int n0 = blockIdx.y * 128;
    const u16* wte = wt + (size_t)e * NGU * NH;
    int ar = tid >> 1, ah = tid & 1;
    int dmarow = (lane >> 3), dmab = (lane & 7) ^ (lane >> 3);

    f32x4 zero = {0.f, 0.f, 0.f, 0.f};
    f32x4 acc[4][4];
#pragma unroll
    for (int i = 0; i < 4; ++i)
#pragma unroll
        for (int j = 0; j < 4; ++j) acc[i][j] = zero;

    __syncthreads();   // tok visible
    int ta = tok[ar];
    const float* xrow = x + (size_t)(ta < 0 ? 0 : ta) * NH + ah * 32;

    for (int kb = 0; kb < NH; kb += 64) {
        s16x8 blk[4];
#pragma unroll
        for (int j = 0; j < 4; ++j) {
            float4 u = {0, 0, 0, 0}, v = {0, 0, 0, 0};
            if (ta >= 0) {
                u = *(const float4*)(xrow + kb + j * 8);
                v = *(const float4*)(xrow + kb + j * 8 + 4);
            }
            s16x8 t;
            t[0] = (short)f2bf(u.x); t[1] = (short)f2bf(u.y);
            t[2] = (short)f2bf(u.z); t[3] = (short)f2bf(u.w);
            t[4] = (short)f2bf(v.x); t[5] = (short)f2bf(v.y);
            t[6] = (short)f2bf(v.z); t[7] = (short)f2bf(v.w);
            blk[j] = t;
        }
        __syncthreads();   // previous iter's LDS reads done
#pragma unroll
        for (int j = 0; j < 4; ++j)
            *(s16x8*)((char*)As + lds_off(ar, ah * 4 + j)) = blk[j];
#pragma unroll
        for (int c = 0; c < 4; ++c) {
            int rloc = (w * 4 + c) * 8 + dmarow;
            lds_dma16(wte + (size_t)(n0 + rloc) * NH + kb + dmab * 8,
                      Bs + (w * 4 + c) * 512);
        }
        __syncthreads();   // drains lgkm + vmcnt (lds-DMA)

#pragma unroll
        for (int kk = 0; kk < 64; kk += 32) {
            s16x8 af[4], bf[4];
#pragma unroll
            for (int i = 0; i < 4; ++i) {
                int rA = wm * 64 + i * 16 + ml;
                af[i] = *(const s16x8*)((char*)As + lds_off(rA, (kk >> 3) + kq));
                int rB = wn * 64 + i * 16 + ml;
                bf[i] = *(const s16x8*)((char*)Bs + lds_off(rB, (kk >> 3) + kq));
            }
#pragma unroll
            for (int mi = 0; mi < 4; ++mi)
#pragma unroll
                for (int ni = 0; ni < 4; ++ni)
                    acc[mi][ni] = __builtin_amdgcn_mfma_f32_16x16x32_bf16(
                        af[mi], bf[ni], acc[mi][ni], 0, 0, 0);
        }
    }

    // epilogue: +bias, pair even/odd cols via shfl, SwiGLU, store bf16 inter
#pragma unroll
    for (int ni = 0; ni < 4; ++ni) {
        int n = n0 + wn * 64 + ni * 16 + ml;
        float bv = bias[e * NGU + n];
#pragma unroll
        for (int mi = 0; mi < 4; ++mi) {
#pragma unroll
            for (int r = 0; r < 4; ++r) {
                float v = acc[mi][ni][r] + bv;
                float pr = __shfl_xor(v, 1, 64);
                float g = (lane & 1) ? pr : v;
                float u = (lane & 1) ? v : pr;
                g = fminf(g, 7.0f);
                u = fminf(fmaxf(u, -7.0f), 7.0f);
                float glu = g / (1.0f + __expf(-1.702f * g));
                float y = (u + 1.0f) * glu;
                int mloc = wm * 64 + mi * 16 + kq * 4 + r;
                if (!(lane & 1) && (m0 + mloc) < Te)
                    inter[(size_t)(seg0 + m0 + mloc) * NI + (n >> 1)] = f2bf(y);
            }
        }
    }
}

// ---------------- fast kernel: down GEMM + bias + weight + scatter-add ----------------
__global__ __launch_bounds__(256) void k_down_f(
        const u16* __restrict__ inter,   // [INTER_ROWS][NI] bf16
        const u16* __restrict__ wt,      // [NE][NH][NI] bf16 (n-major)
        const float* __restrict__ bias,  // [NE][NH]
        const float* __restrict__ rw,    // [MTOK][NE]
        const int* __restrict__ seg, const int* __restrict__ desc,
        const int* __restrict__ slot_of,
        float* __restrict__ out) {       // [MTOK][NH] fp32 (pre-zeroed)
    int d = desc[blockIdx.x];
    if (d < 0) return;
    int e = d >> 16, mt = d & 0xffff;
    int seg0 = seg[e], Te = seg[e + 1] - seg0, m0 = mt * 128;

    __shared__ __align__(16) u16 As[128 * 64];
    __shared__ __align__(16) u16 Bs[128 * 64];

    int tid = threadIdx.x;
    int lane = tid & 63, w = tid >> 6;
    int ml = lane & 15, kq = lane >> 4;
    int wm = w >> 1, wn = w & 1;
    int n0 = blockIdx.y * 128;
    const u16* wte = wt + (size_t)e * NH * NI;
    int dmarow = (lane >> 3), dmab = (lane & 7) ^ (lane >> 3);

    f32x4 zero = {0.f, 0.f, 0.f, 0.f};
    f32x4 acc[4][4];
#pragma unroll
    for (int i = 0; i < 4; ++i)
#pragma unroll
        for (int j = 0; j < 4; ++j) acc[i][j] = zero;

    for (int kb = 0; kb < NI; kb += 64) {
        __syncthreads();
#pragma unroll
        for (int c = 0; c < 4; ++c) {
            int rloc = (w * 4 + c) * 8 + dmarow;
            lds_dma16(inter + (size_t)(seg0 + m0 + rloc) * NI + kb + dmab * 8,
                      As + (w * 4 + c) * 512);
            lds_dma16(wte + (size_t)(n0 + rloc) * NI + kb + dmab * 8,
                      Bs + (w * 4 + c) * 512);
        }
        __syncthreads();

#pragma unroll
        for (int kk = 0; kk < 64; kk += 32) {
            s16x8 af[4], bf[4];
#pragma unroll
            for (int i = 0; i < 4; ++i) {
                int rA = wm * 64 + i * 16 + ml;
                af[i] = *(const s16x8*)((char*)As + lds_off(rA, (kk >> 3) + kq));
                int rB = wn * 64 + i * 16 + ml;
                bf[i] = *(const s16x8*)((char*)Bs + lds_off(rB, (kk >> 3) + kq));
            }
#pragma unroll
            for (int mi = 0; mi < 4; ++mi)
#pragma unroll
                for (int ni = 0; ni < 4; ++ni)
                    acc[mi][ni] = __builtin_amdgcn_mfma_f32_16x16x32_bf16(
                        af[mi], bf[ni], acc[mi][ni], 0, 0, 0);
        }
    }

    float bv[4];
#pragma unroll
    for (int ni = 0; ni < 4; ++ni) bv[ni] = bias[e * NH + n0 + wn * 64 + ni * 16 + ml];

#pragma unroll
    for (int mi = 0; mi < 4; ++mi) {
#pragma unroll
        for (int r = 0; r < 4; ++r) {
            int mloc = wm * 64 + mi * 16 + kq * 4 + r;
            if ((m0 + mloc) < Te) {
                int slot = slot_of[seg0 + m0 + mloc];
                int token = slot >> 1;
                float wgt = rw[token * NE + e];
#pragma unroll
                for (int ni = 0; ni < 4; ++ni) {
                    int n = n0 + wn * 64 + ni * 16 + ml;
                    atomicAdd(&out[(size_t)token * NH + n], (acc[mi][ni][r] + bv[ni]) * wgt);
                }
            }
        }
    }
}

// ---------------- slow-path kernels (round-2, proven) ----------------
__global__ __launch_bounds__(256) void k_gateup_s(
        const float* __restrict__ x, const float* __restrict__ w,
        const float* __restrict__ bias,
        const int* __restrict__ seg, const int* __restrict__ desc,
        const int* __restrict__ slot_of, u16* __restrict__ inter) {
    int d = desc[blockIdx.x];
    if (d < 0) return;
    int e = d >> 16, mt = d & 0xffff;
    int seg0 = seg[e], Te = seg[e + 1] - seg0, m0 = mt * 64;
    __shared__ u16 As[64 * 40];
    __shared__ int tok[64];
    int tid = threadIdx.x;
    if (tid < 64) {
        int m = m0 + tid;
        tok[tid] = (m < Te) ? (slot_of[seg0 + m] >> 1) : -1;
    }
    __syncthreads();
    int lane = tid & 63, wave = tid >> 6;
    int arow = tid >> 2, acol = (tid & 3) * 8;
    int ta = tok[arow];
    int kq = lane >> 4, ml = lane & 15;
    int nb = blockIdx.y * 128 + wave * 32;
    const float* wp = w + (size_t)e * NH * NGU;
    f32x4 zero = {0.f, 0.f, 0.f, 0.f};
    f32x4 acc[4][2];
#pragma unroll
    for (int i = 0; i < 4; ++i) { acc[i][0] = zero; acc[i][1] = zero; }
    for (int kb = 0; kb < NH; kb += 32) {
        float4 a0 = {0, 0, 0, 0}, a1 = {0, 0, 0, 0};
        if (ta >= 0) {
            const float* xp = x + (size_t)ta * NH + kb + acol;
            a0 = *(const float4*)xp; a1 = *(const float4*)(xp + 4);
        }
        s16x8 av;
        av[0] = (short)f2bf(a0.x); av[1] = (short)f2bf(a0.y);
        av[2] = (short)f2bf(a0.z); av[3] = (short)f2bf(a0.w);
        av[4] = (short)f2bf(a1.x); av[5] = (short)f2bf(a1.y);
        av[6] = (short)f2bf(a1.z); av[7] = (short)f2bf(a1.w);
        __syncthreads();
        *(s16x8*)&As[arow * 40 + acol] = av;
        __syncthreads();
        s16x8 afr[4];
#pragma unroll
        for (int msi = 0; msi < 4; ++msi)
            afr[msi] = *(const s16x8*)&As[(msi * 16 + ml) * 40 + kq * 8];
        s16x8 bfr[2];
#pragma unroll
        for (int s = 0; s < 2; ++s) {
            const float* bp = wp + (size_t)(kb + kq * 8) * NGU + nb + s * 16 + ml;
#pragma unroll
            for (int j = 0; j < 8; ++j) bfr[s][j] = (short)f2bf(bp[(size_t)j * NGU]);
        }
#pragma unroll
        for (int msi = 0; msi < 4; ++msi)
#pragma unroll
            for (int s = 0; s < 2; ++s)
                acc[msi][s] = __builtin_amdgcn_mfma_f32_16x16x32_bf16(
                    afr[msi], bfr[s], acc[msi][s], 0, 0, 0);
    }
#pragma unroll
    for (int s = 0; s < 2; ++s) {
        int n = nb + s * 16 + ml;
        float bv = bias[e * NGU + n];
#pragma unroll
        for (int msi = 0; msi < 4; ++msi) {
#pragma unroll
            for (int r = 0; r < 4; ++r) {
                float v = acc[msi][s][r] + bv;
                float pr = __shfl_xor(v, 1, 64);
                float g = (lane & 1) ? pr : v;
                float u = (lane & 1) ? v : pr;
                g = fminf(g, 7.0f);
                u = fminf(fmaxf(u, -7.0f), 7.0f);
                float glu = g / (1.0f + __expf(-1.702f * g));
                float y = (u + 1.0f) * glu;
                int mrow = m0 + msi * 16 + kq * 4 + r;
                if (!(lane & 1) && mrow < Te)
                    inter[(size_t)(seg0 + mrow) * NI + (n >> 1)] = f2bf(y);
            }
        }
    }
}

__global__ __launch_bounds__(256) void k_down_s(
        const u16* __restrict__ inter, const float* __restrict__ w,
        const float* __restrict__ bias, const float* __restrict__ rw,
        const int* __restrict__ seg, const int* __restrict__ desc,
        const int* __restrict__ slot_of, float* __restrict__ out) {
    int d = desc[blockIdx.x];
    if (d < 0) return;
    int e = d >> 16, mt = d & 0xffff;
    int seg0 = seg[e], Te = seg[e + 1] - seg0, m0 = mt * 64;
    __shared__ u16 As[64 * 40];
    int tid = threadIdx.x;
    int lane = tid & 63, wave = tid >> 6;
    int arow = tid >> 2, acol = (tid & 3) * 8;
    bool avalid = (m0 + arow) < Te;
    int kq = lane >> 4, ml = lane & 15;
    int nb = blockIdx.y * 128 + wave * 32;
    const float* wp = w + (size_t)e * NI * NH;
    f32x4 zero = {0.f, 0.f, 0.f, 0.f};
    f32x4 acc[4][2];
#pragma unroll
    for (int i = 0; i < 4; ++i) { acc[i][0] = zero; acc[i][1] = zero; }
    for (int kb = 0; kb < NI; kb += 32) {
        s16x8 av = {0, 0, 0, 0, 0, 0, 0, 0};
        if (avalid) av = *(const s16x8*)(inter + (size_t)(seg0 + m0 + arow) * NI + kb + acol);
        __syncthreads();
        *(s16x8*)&As[arow * 40 + acol] = av;
        __syncthreads();
        s16x8 afr[4];
#pragma unroll
        for (int msi = 0; msi < 4; ++msi)
            afr[msi] = *(const s16x8*)&As[(msi * 16 + ml) * 40 + kq * 8];
        s16x8 bfr[2];
#pragma unroll
        for (int s = 0; s < 2; ++s) {
            const float* bp = wp + (size_t)(kb + kq * 8) * NH + nb + s * 16 + ml;
#pragma unroll
            for (int j = 0; j < 8; ++j) bfr[s][j] = (short)f2bf(bp[(size_t)j * NH]);
        }
#pragma unroll
        for (int msi = 0; msi < 4; ++msi)
#pragma unroll
            for (int s = 0; s < 2; ++s)
                acc[msi][s] = __builtin_amdgcn_mfma_f32_16x16x32_bf16(
                    afr[msi], bfr[s], acc[msi][s], 0, 0, 0);
    }
    float bv[2];
    bv[0] = bias[e * NH + nb + ml];
    bv[1] = bias[e * NH + nb + 16 + ml];
#pragma unroll
    for (int msi = 0; msi < 4; ++msi) {
#pragma unroll
        for (int r = 0; r < 4; ++r) {
            int mrow = m0 + msi * 16 + kq * 4 + r;
            if (mrow < Te) {
                int slot = slot_of[seg0 + mrow];
                int token = slot >> 1;
                float wgt = rw[token * NE + e];
#pragma unroll
                for (int s = 0; s < 2; ++s) {
                    int n = nb + s * 16 + ml;
                    atomicAdd(&out[(size_t)token * NH + n], (acc[msi][s][r] + bv[s]) * wgt);
                }
            }
        }
    }
}

extern "C" void kernel_launch(void* const* d_in, const int* in_sizes, int n_in,
                              void* d_out, int out_size, void* d_ws, size_t ws_size,
                              hipStream_t stream) {
    const float* x   = (const float*)d_in[0];
    const int*   ri  = (const int*)d_in[1];
    const float* rw  = (const float*)d_in[2];
    const float* wgu = (const float*)d_in[3];
    const float* bgu = (const float*)d_in[4];
    const float* wd  = (const float*)d_in[5];
    const float* bd  = (const float*)d_in[6];
    float* out = (float*)d_out;

    char* ws = (char*)d_ws;
    int* seg     = (int*)(ws + WS_SEG);
    int* d64     = (int*)(ws + WS_DESC64);
    int* d128    = (int*)(ws + WS_DESC128);
    int* slot_of = (int*)(ws + WS_SLOT);
    u16* inter   = (u16*)(ws + WS_INTER);

    hipMemsetAsync(out, 0, (size_t)MTOK * NH * sizeof(float), stream);
    hipLaunchKernelGGL(k_build, dim3(1), dim3(256), 0, stream, ri, seg, d64, d128, slot_of);

    if (ws_size >= WS_NEED_FAST) {
        u16* wtgu = (u16*)(ws + WS_WTGU);
        u16* wtd  = (u16*)(ws + WS_WTD);
        hipLaunchKernelGGL(k_tr, dim3(NGU / 64, NH / 64, NE), dim3(256), 0, stream,
                           wgu, wtgu, NH, NGU);
        hipLaunchKernelGGL(k_tr, dim3(NH / 64, NI / 64, NE), dim3(256), 0, stream,
                           wd, wtd, NI, NH);
        hipLaunchKernelGGL(k_gateup_f, dim3(MAXT128, NGU / 128), dim3(256), 0, stream,
                           x, wtgu, bgu, seg, d128, slot_of, inter);
        hipLaunchKernelGGL(k_down_f, dim3(MAXT128, NH / 128), dim3(256), 0, stream,
                           inter, wtd, bd, rw, seg, d128, slot_of, out);
    } else {
        hipLaunchKernelGGL(k_gateup_s, dim3(MAXT64, NGU / 128), dim3(256), 0, stream,
                           x, wgu, bgu, seg, d64, slot_of, inter);
        hipLaunchKernelGGL(k_down_s, dim3(MAXT64, NH / 128), dim3(256), 0, stream,
                           inter, wd, bd, rw, seg, d64, slot_of, out);
    }
}

// Round 4
// 245.129 us; speedup vs baseline: 1.2377x; 1.1126x over previous
//
#include <hip/hip_runtime.h>

#define NE 8
#define NH 1024
#define NI 1024
#define NGU 2048
#define MTOK 2048
#define TSLOT 4096

#define MAXT64 80     // slow path: 64-row tiles
#define MAXT128 40    // fast path: 128-row tiles

typedef short s16x8 __attribute__((ext_vector_type(8)));
typedef float f32x4 __attribute__((ext_vector_type(4)));
typedef unsigned short u16;

// ---- ws layout (bytes) ----
#define WS_SEG      0
#define WS_DESC64   64
#define WS_DESC128  384
#define WS_SLOT     1024
#define WS_INTER    32768
#define INTER_ROWS  4224                    // 4096 + 128 pad rows (tile overrun)
#define WS_WTGU     8683520UL               // 32768 + 4224*1024*2
#define WS_R        42237952UL              // + 8*2048*1024*2 ; A_sorted then wtd
#define WS_NEED_FAST 59015168UL             // + 8*1024*1024*2 (wtd is the larger user of R)

__device__ inline u16 f2bf(float f) {
    unsigned u = __builtin_bit_cast(unsigned, f);
    u += 0x7fffu + ((u >> 16) & 1u);
    return (u16)(u >> 16);
}

__device__ inline void lds_dma16(const u16* g, u16* l) {
    __builtin_amdgcn_global_load_lds(
        (const __attribute__((address_space(1))) unsigned int*)g,
        (__attribute__((address_space(3))) unsigned int*)l, 16, 0, 0);
}

// swizzled LDS byte offset: row-stride 128B (64 bf16), 16B chunks XORed by row&7
__device__ inline int lds_off(int row, int blk) {
    return (row << 7) | (((blk ^ (row & 7)) & 7) << 4);
}

// ---------------- kernel 1: expert-sort + tile descriptors ----------------
__global__ void k_build(const int* __restrict__ ridx, int* __restrict__ seg,
                        int* __restrict__ d64, int* __restrict__ d128,
                        int* __restrict__ slot_of) {
    __shared__ int cnt[NE];
    __shared__ int cur[NE];
    int tid = threadIdx.x;
    if (tid < NE) cnt[tid] = 0;
    __syncthreads();
    for (int s = tid; s < TSLOT; s += blockDim.x) atomicAdd(&cnt[ridx[s] & 7], 1);
    __syncthreads();
    if (tid == 0) {
        int a = 0;
        for (int e = 0; e < NE; ++e) { seg[e] = a; cur[e] = a; a += cnt[e]; }
        seg[NE] = a;
        int nt = 0;
        for (int e = 0; e < NE; ++e)
            for (int m0 = 0; m0 < cnt[e]; m0 += 64) d64[nt++] = (e << 16) | (m0 / 64);
        for (; nt < MAXT64; ++nt) d64[nt] = -1;
        nt = 0;
        for (int e = 0; e < NE; ++e)
            for (int m0 = 0; m0 < cnt[e]; m0 += 128) d128[nt++] = (e << 16) | (m0 / 128);
        for (; nt < MAXT128; ++nt) d128[nt] = -1;
    }
    __syncthreads();
    for (int s = tid; s < TSLOT; s += blockDim.x) {
        int e = ridx[s] & 7;
        int p = atomicAdd(&cur[e], 1);
        slot_of[p] = s;
    }
}

// ---------------- gather x rows into expert-sorted bf16 A ----------------
__global__ __launch_bounds__(256) void k_gather(const float* __restrict__ x,
                                                const int* __restrict__ slot_of,
                                                u16* __restrict__ A) {
    int r = blockIdx.x;                       // 0..TSLOT-1
    int token = slot_of[r] >> 1;
    float4 v = ((const float4*)(x + (size_t)token * NH))[threadIdx.x];
    ushort4 o;
    o.x = f2bf(v.x); o.y = f2bf(v.y); o.z = f2bf(v.z); o.w = f2bf(v.w);
    ((ushort4*)(A + (size_t)r * NH))[threadIdx.x] = o;
}

// ---------------- transpose+convert: W[e][K][N] fp32 -> WT[e][N][K] bf16 ----------------
__global__ __launch_bounds__(256) void k_tr(const float* __restrict__ W,
                                            u16* __restrict__ WT, int K, int N) {
    __shared__ u16 T[64][72];
    int tid = threadIdx.x;
    const float* in = W + (size_t)blockIdx.z * K * N;
    u16* out = WT + (size_t)blockIdx.z * N * K;
    int n0 = blockIdx.x * 64, k0 = blockIdx.y * 64;
#pragma unroll
    for (int p = 0; p < 4; ++p) {
        int idx = p * 256 + tid;
        int kr = idx >> 4, nc = (idx & 15) * 4;
        float4 v = *(const float4*)(in + (size_t)(k0 + kr) * N + n0 + nc);
        T[nc + 0][kr] = f2bf(v.x); T[nc + 1][kr] = f2bf(v.y);
        T[nc + 2][kr] = f2bf(v.z); T[nc + 3][kr] = f2bf(v.w);
    }
    __syncthreads();
#pragma unroll
    for (int p = 0; p < 2; ++p) {
        int idx = p * 256 + tid;
        int nr = idx >> 3, kc = (idx & 7) * 8;
        s16x8 vv = *(const s16x8*)&T[nr][kc];
        *(s16x8*)(out + (size_t)(n0 + nr) * K + k0 + kc) = vv;
    }
}

// ---------------- fast gate_up: 128x64 tile, all-DMA staging ----------------
__global__ __launch_bounds__(256) void k_gateup_f(
        const u16* __restrict__ A,       // [INTER_ROWS][NH] bf16, expert-sorted
        const u16* __restrict__ wt,      // [NE][NGU][NH] bf16 (n-major)
        const float* __restrict__ bias,  // [NE][NGU]
        const int* __restrict__ seg, const int* __restrict__ desc,
        u16* __restrict__ inter) {       // [INTER_ROWS][NI] bf16
    int d = desc[blockIdx.x];
    if (d < 0) return;
    int e = d >> 16, mt = d & 0xffff;
    int seg0 = seg[e], Te = seg[e + 1] - seg0, m0 = mt * 128;

    __shared__ __align__(16) u16 As[128 * 64];
    __shared__ __align__(16) u16 Bs[64 * 64];

    int tid = threadIdx.x;
    int lane = tid & 63, w = tid >> 6;
    int ml = lane & 15, kq = lane >> 4;
    int wm = w >> 1, wn = w & 1;
    int n0 = blockIdx.y * 64;
    const u16* wte = wt + (size_t)e * NGU * NH;
    int dr = lane >> 3, db = (lane & 7) ^ dr;
    const u16* Ag = A + (size_t)(seg0 + m0) * NH;

    f32x4 zero = {0.f, 0.f, 0.f, 0.f};
    f32x4 acc[4][2];
#pragma unroll
    for (int i = 0; i < 4; ++i) { acc[i][0] = zero; acc[i][1] = zero; }

    for (int kb = 0; kb < NH; kb += 64) {
        __syncthreads();
#pragma unroll
        for (int c = 0; c < 4; ++c) {
            int row = c * 32 + w * 8 + dr;
            lds_dma16(Ag + (size_t)row * NH + kb + db * 8, As + c * 2048 + w * 512);
        }
#pragma unroll
        for (int c = 0; c < 2; ++c) {
            int row = c * 32 + w * 8 + dr;
            lds_dma16(wte + (size_t)(n0 + row) * NH + kb + db * 8, Bs + c * 2048 + w * 512);
        }
        __syncthreads();

#pragma unroll
        for (int kk = 0; kk < 64; kk += 32) {
            s16x8 af[4], bf[2];
#pragma unroll
            for (int i = 0; i < 4; ++i)
                af[i] = *(const s16x8*)((char*)As + lds_off(wm * 64 + i * 16 + ml, (kk >> 3) + kq));
#pragma unroll
            for (int i = 0; i < 2; ++i)
                bf[i] = *(const s16x8*)((char*)Bs + lds_off(wn * 32 + i * 16 + ml, (kk >> 3) + kq));
#pragma unroll
            for (int mi = 0; mi < 4; ++mi)
#pragma unroll
                for (int ni = 0; ni < 2; ++ni)
                    acc[mi][ni] = __builtin_amdgcn_mfma_f32_16x16x32_bf16(
                        af[mi], bf[ni], acc[mi][ni], 0, 0, 0);
        }
    }

#pragma unroll
    for (int ni = 0; ni < 2; ++ni) {
        int n = n0 + wn * 32 + ni * 16 + ml;
        float bv = bias[e * NGU + n];
#pragma unroll
        for (int mi = 0; mi < 4; ++mi) {
#pragma unroll
            for (int r = 0; r < 4; ++r) {
                float v = acc[mi][ni][r] + bv;
                float pr = __shfl_xor(v, 1, 64);
                float g = (lane & 1) ? pr : v;
                float u = (lane & 1) ? v : pr;
                g = fminf(g, 7.0f);
                u = fminf(fmaxf(u, -7.0f), 7.0f);
                float glu = g / (1.0f + __expf(-1.702f * g));
                float y = (u + 1.0f) * glu;
                int mloc = wm * 64 + mi * 16 + kq * 4 + r;
                if (!(lane & 1) && (m0 + mloc) < Te)
                    inter[(size_t)(seg0 + m0 + mloc) * NI + (n >> 1)] = f2bf(y);
            }
        }
    }
}

// ---------------- fast down: 128x64 tile, split-K x2, scatter-add ----------------
__global__ __launch_bounds__(256) void k_down_f(
        const u16* __restrict__ inter,   // [INTER_ROWS][NI] bf16
        const u16* __restrict__ wt,      // [NE][NH][NI] bf16 (n-major)
        const float* __restrict__ bias,  // [NE][NH]
        const float* __restrict__ rw,    // [MTOK][NE]
        const int* __restrict__ seg, const int* __restrict__ desc,
        const int* __restrict__ slot_of,
        float* __restrict__ out) {       // [MTOK][NH] fp32 (pre-zeroed)
    int d = desc[blockIdx.x];
    if (d < 0) return;
    int e = d >> 16, mt = d & 0xffff;
    int seg0 = seg[e], Te = seg[e + 1] - seg0, m0 = mt * 128;
    int kz = blockIdx.z;                 // split-K half

    __shared__ __align__(16) u16 As[128 * 64];
    __shared__ __align__(16) u16 Bs[64 * 64];

    int tid = threadIdx.x;
    int lane = tid & 63, w = tid >> 6;
    int ml = lane & 15, kq = lane >> 4;
    int wm = w >> 1, wn = w & 1;
    int n0 = blockIdx.y * 64;
    const u16* wte = wt + (size_t)e * NH * NI;
    int dr = lane >> 3, db = (lane & 7) ^ dr;
    const u16* Ig = inter + (size_t)(seg0 + m0) * NI;

    f32x4 zero = {0.f, 0.f, 0.f, 0.f};
    f32x4 acc[4][2];
#pragma unroll
    for (int i = 0; i < 4; ++i) { acc[i][0] = zero; acc[i][1] = zero; }

    int kbeg = kz * (NI / 2), kend = kbeg + NI / 2;
    for (int kb = kbeg; kb < kend; kb += 64) {
        __syncthreads();
#pragma unroll
        for (int c = 0; c < 4; ++c) {
            int row = c * 32 + w * 8 + dr;
            lds_dma16(Ig + (size_t)row * NI + kb + db * 8, As + c * 2048 + w * 512);
        }
#pragma unroll
        for (int c = 0; c < 2; ++c) {
            int row = c * 32 + w * 8 + dr;
            lds_dma16(wte + (size_t)(n0 + row) * NI + kb + db * 8, Bs + c * 2048 + w * 512);
        }
        __syncthreads();

#pragma unroll
        for (int kk = 0; kk < 64; kk += 32) {
            s16x8 af[4], bf[2];
#pragma unroll
            for (int i = 0; i < 4; ++i)
                af[i] = *(const s16x8*)((char*)As + lds_off(wm * 64 + i * 16 + ml, (kk >> 3) + kq));
#pragma unroll
            for (int i = 0; i < 2; ++i)
                bf[i] = *(const s16x8*)((char*)Bs + lds_off(wn * 32 + i * 16 + ml, (kk >> 3) + kq));
#pragma unroll
            for (int mi = 0; mi < 4; ++mi)
#pragma unroll
                for (int ni = 0; ni < 2; ++ni)
                    acc[mi][ni] = __builtin_amdgcn_mfma_f32_16x16x32_bf16(
                        af[mi], bf[ni], acc[mi][ni], 0, 0, 0);
        }
    }

    float bv[2];
#pragma unroll
    for (int ni = 0; ni < 2; ++ni)
        bv[ni] = (kz == 0) ? bias[e * NH + n0 + wn * 32 + ni * 16 + ml] : 0.0f;

#pragma unroll
    for (int mi = 0; mi < 4; ++mi) {
#pragma unroll
        for (int r = 0; r < 4; ++r) {
            int mloc = wm * 64 + mi * 16 + kq * 4 + r;
            if ((m0 + mloc) < Te) {
                int slot = slot_of[seg0 + m0 + mloc];
                int token = slot >> 1;
                float wgt = rw[token * NE + e];
#pragma unroll
                for (int ni = 0; ni < 2; ++ni) {
                    int n = n0 + wn * 32 + ni * 16 + ml;
                    atomicAdd(&out[(size_t)token * NH + n], (acc[mi][ni][r] + bv[ni]) * wgt);
                }
            }
        }
    }
}

// ---------------- slow-path kernels (round-2, proven) ----------------
__global__ __launch_bounds__(256) void k_gateup_s(
        const float* __restrict__ x, const float* __restrict__ w,
        const float* __restrict__ bias,
        const int* __restrict__ seg, const int* __restrict__ desc,
        const int* __restrict__ slot_of, u16* __restrict__ inter) {
    int d = desc[blockIdx.x];
    if (d < 0) return;
    int e = d >> 16, mt = d & 0xffff;
    int seg0 = seg[e], Te = seg[e + 1] - seg0, m0 = mt * 64;
    __shared__ u16 As[64 * 40];
    __shared__ int tok[64];
    int tid = threadIdx.x;
    if (tid < 64) {
        int m = m0 + tid;
        tok[tid] = (m < Te) ? (slot_of[seg0 + m] >> 1) : -1;
    }
    __syncthreads();
    int lane = tid & 63, wave = tid >> 6;
    int arow = tid >> 2, acol = (tid & 3) * 8;
    int ta = tok[arow];
    int kq = lane >> 4, ml = lane & 15;
    int nb = blockIdx.y * 128 + wave * 32;
    const float* wp = w + (size_t)e * NH * NGU;
    f32x4 zero = {0.f, 0.f, 0.f, 0.f};
    f32x4 acc[4][2];
#pragma unroll
    for (int i = 0; i < 4; ++i) { acc[i][0] = zero; acc[i][1] = zero; }
    for (int kb = 0; kb < NH; kb += 32) {
        float4 a0 = {0, 0, 0, 0}, a1 = {0, 0, 0, 0};
        if (ta >= 0) {
            const float* xp = x + (size_t)ta * NH + kb + acol;
            a0 = *(const float4*)xp; a1 = *(const float4*)(xp + 4);
        }
        s16x8 av;
        av[0] = (short)f2bf(a0.x); av[1] = (short)f2bf(a0.y);
        av[2] = (short)f2bf(a0.z); av[3] = (short)f2bf(a0.w);
        av[4] = (short)f2bf(a1.x); av[5] = (short)f2bf(a1.y);
        av[6] = (short)f2bf(a1.z); av[7] = (short)f2bf(a1.w);
        __syncthreads();
        *(s16x8*)&As[arow * 40 + acol] = av;
        __syncthreads();
        s16x8 afr[4];
#pragma unroll
        for (int msi = 0; msi < 4; ++msi)
            afr[msi] = *(const s16x8*)&As[(msi * 16 + ml) * 40 + kq * 8];
        s16x8 bfr[2];
#pragma unroll
        for (int s = 0; s < 2; ++s) {
            const float* bp = wp + (size_t)(kb + kq * 8) * NGU + nb + s * 16 + ml;
#pragma unroll
            for (int j = 0; j < 8; ++j) bfr[s][j] = (short)f2bf(bp[(size_t)j * NGU]);
        }
#pragma unroll
        for (int msi = 0; msi < 4; ++msi)
#pragma unroll
            for (int s = 0; s < 2; ++s)
                acc[msi][s] = __builtin_amdgcn_mfma_f32_16x16x32_bf16(
                    afr[msi], bfr[s], acc[msi][s], 0, 0, 0);
    }
#pragma unroll
    for (int s = 0; s < 2; ++s) {
        int n = nb + s * 16 + ml;
        float bv = bias[e * NGU + n];
#pragma unroll
        for (int msi = 0; msi < 4; ++msi) {
#pragma unroll
            for (int r = 0; r < 4; ++r) {
                float v = acc[msi][s][r] + bv;
                float pr = __shfl_xor(v, 1, 64);
                float g = (lane & 1) ? pr : v;
                float u = (lane & 1) ? v : pr;
                g = fminf(g, 7.0f);
                u = fminf(fmaxf(u, -7.0f), 7.0f);
                float glu = g / (1.0f + __expf(-1.702f * g));
                float y = (u + 1.0f) * glu;
                int mrow = m0 + msi * 16 + kq * 4 + r;
                if (!(lane & 1) && mrow < Te)
                    inter[(size_t)(seg0 + mrow) * NI + (n >> 1)] = f2bf(y);
            }
        }
    }
}

__global__ __launch_bounds__(256) void k_down_s(
        const u16* __restrict__ inter, const float* __restrict__ w,
        const float* __restrict__ bias, const float* __restrict__ rw,
        const int* __restrict__ seg, const int* __restrict__ desc,
        const int* __restrict__ slot_of, float* __restrict__ out) {
    int d = desc[blockIdx.x];
    if (d < 0) return;
    int e = d >> 16, mt = d & 0xffff;
    int seg0 = seg[e], Te = seg[e + 1] - seg0, m0 = mt * 64;
    __shared__ u16 As[64 * 40];
    int tid = threadIdx.x;
    int lane = tid & 63, wave = tid >> 6;
    int arow = tid >> 2, acol = (tid & 3) * 8;
    bool avalid = (m0 + arow) < Te;
    int kq = lane >> 4, ml = lane & 15;
    int nb = blockIdx.y * 128 + wave * 32;
    const float* wp = w + (size_t)e * NI * NH;
    f32x4 zero = {0.f, 0.f, 0.f, 0.f};
    f32x4 acc[4][2];
#pragma unroll
    for (int i = 0; i < 4; ++i) { acc[i][0] = zero; acc[i][1] = zero; }
    for (int kb = 0; kb < NI; kb += 32) {
        s16x8 av = {0, 0, 0, 0, 0, 0, 0, 0};
        if (avalid) av = *(const s16x8*)(inter + (size_t)(seg0 + m0 + arow) * NI + kb + acol);
        __syncthreads();
        *(s16x8*)&As[arow * 40 + acol] = av;
        __syncthreads();
        s16x8 afr[4];
#pragma unroll
        for (int msi = 0; msi < 4; ++msi)
            afr[msi] = *(const s16x8*)&As[(msi * 16 + ml) * 40 + kq * 8];
        s16x8 bfr[2];
#pragma unroll
        for (int s = 0; s < 2; ++s) {
            const float* bp = wp + (size_t)(kb + kq * 8) * NH + nb + s * 16 + ml;
#pragma unroll
            for (int j = 0; j < 8; ++j) bfr[s][j] = (short)f2bf(bp[(size_t)j * NH]);
        }
#pragma unroll
        for (int msi = 0; msi < 4; ++msi)
#pragma unroll
            for (int s = 0; s < 2; ++s)
                acc[msi][s] = __builtin_amdgcn_mfma_f32_16x16x32_bf16(
                    afr[msi], bfr[s], acc[msi][s], 0, 0, 0);
    }
    float bv[2];
    bv[0] = bias[e * NH + nb + ml];
    bv[1] = bias[e * NH + nb + 16 + ml];
#pragma unroll
    for (int msi = 0; msi < 4; ++msi) {
#pragma unroll
        for (int r = 0; r < 4; ++r) {
            int mrow = m0 + msi * 16 + kq * 4 + r;
            if (mrow < Te) {
                int slot = slot_of[seg0 + mrow];
                int token = slot >> 1;
                float wgt = rw[token * NE + e];
#pragma unroll
                for (int s = 0; s < 2; ++s) {
                    int n = nb + s * 16 + ml;
                    atomicAdd(&out[(size_t)token * NH + n], (acc[msi][s][r] + bv[s]) * wgt);
                }
            }
        }
    }
}

extern "C" void kernel_launch(void* const* d_in, const int* in_sizes, int n_in,
                              void* d_out, int out_size, void* d_ws, size_t ws_size,
                              hipStream_t stream) {
    const float* x   = (const float*)d_in[0];
    const int*   ri  = (const int*)d_in[1];
    const float* rw  = (const float*)d_in[2];
    const float* wgu = (const float*)d_in[3];
    const float* bgu = (const float*)d_in[4];
    const float* wd  = (const float*)d_in[5];
    const float* bd  = (const float*)d_in[6];
    float* out = (float*)d_out;

    char* ws = (char*)d_ws;
    int* seg     = (int*)(ws + WS_SEG);
    int* d64     = (int*)(ws + WS_DESC64);
    int* d128    = (int*)(ws + WS_DESC128);
    int* slot_of = (int*)(ws + WS_SLOT);
    u16* inter   = (u16*)(ws + WS_INTER);

    hipMemsetAsync(out, 0, (size_t)MTOK * NH * sizeof(float), stream);
    hipLaunchKernelGGL(k_build, dim3(1), dim3(256), 0, stream, ri, seg, d64, d128, slot_of);

    if (ws_size >= WS_NEED_FAST) {
        u16* wtgu  = (u16*)(ws + WS_WTGU);
        u16* regR  = (u16*)(ws + WS_R);      // A_sorted during gate_up, wtd during down
        hipLaunchKernelGGL(k_tr, dim3(NGU / 64, NH / 64, NE), dim3(256), 0, stream,
                           wgu, wtgu, NH, NGU);
        hipLaunchKernelGGL(k_gather, dim3(TSLOT), dim3(256), 0, stream, x, slot_of, regR);
        hipLaunchKernelGGL(k_gateup_f, dim3(MAXT128, NGU / 64), dim3(256), 0, stream,
                           regR, wtgu, bgu, seg, d128, inter);
        hipLaunchKernelGGL(k_tr, dim3(NH / 64, NI / 64, NE), dim3(256), 0, stream,
                           wd, regR, NI, NH);
        hipLaunchKernelGGL(k_down_f, dim3(MAXT128, NH / 64, 2), dim3(256), 0, stream,
                           inter, regR, bd, rw, seg, d128, slot_of, out);
    } else {
        hipLaunchKernelGGL(k_gateup_s, dim3(MAXT64, NGU / 128), dim3(256), 0, stream,
                           x, wgu, bgu, seg, d64, slot_of, inter);
        hipLaunchKernelGGL(k_down_s, dim3(MAXT64, NH / 128), dim3(256), 0, stream,
                           inter, wd, bd, rw, seg, d64, slot_of, out);
    }
}

// Round 5
// 238.854 us; speedup vs baseline: 1.2703x; 1.0263x over previous
//
#include <hip/hip_runtime.h>

#define NE 8
#define NH 1024
#define NI 1024
#define NGU 2048
#define MTOK 2048
#define TSLOT 4096

#define MAXT64 80     // slow path: 64-row tiles
#define MAXT128 40    // fast path: 128-row tiles

typedef short s16x8 __attribute__((ext_vector_type(8)));
typedef float f32x4 __attribute__((ext_vector_type(4)));
typedef unsigned short u16;

// ---- ws layout (bytes) ----
#define WS_SEG      0
#define WS_DESC64   64
#define WS_DESC128  384
#define WS_SLOT     1024          // 4096 ints -> 17408
#define WS_POS      17408         // 4096 ints -> 33792
#define WS_INTER    33792         // bf16 [4096][1024] -> +8388608 = 8422400
#define WS_AREG     8422400UL     // A_sorted bf16 [4096][1024] (8.39MB) then dA fp32 [4096][1024] (16.78MB)
#define WS_WREG     25199616UL    // WT_gu bf16 (33.55MB); then WT_d (16.78MB) + dB fp32 (16.78MB)
#define WS_DB_OFF   16777216UL
#define WS_NEED_FAST 58754048UL

__device__ inline u16 f2bf(float f) {
    unsigned u = __builtin_bit_cast(unsigned, f);
    u += 0x7fffu + ((u >> 16) & 1u);
    return (u16)(u >> 16);
}

__device__ inline void lds_dma16(const u16* g, u16* l) {
    __builtin_amdgcn_global_load_lds(
        (const __attribute__((address_space(1))) unsigned int*)g,
        (__attribute__((address_space(3))) unsigned int*)l, 16, 0, 0);
}

// swizzled LDS byte offset: row-stride 128B (64 bf16), 16B chunks XORed by row&7
__device__ inline int lds_off(int row, int blk) {
    return (row << 7) | (((blk ^ (row & 7)) & 7) << 4);
}

// ---------------- kernel 1: expert-sort + tile descriptors ----------------
__global__ void k_build(const int* __restrict__ ridx, int* __restrict__ seg,
                        int* __restrict__ d64, int* __restrict__ d128,
                        int* __restrict__ slot_of, int* __restrict__ pos_of) {
    __shared__ int cnt[NE];
    __shared__ int cur[NE];
    int tid = threadIdx.x;
    if (tid < NE) cnt[tid] = 0;
    __syncthreads();
    for (int s = tid; s < TSLOT; s += blockDim.x) atomicAdd(&cnt[ridx[s] & 7], 1);
    __syncthreads();
    if (tid == 0) {
        int a = 0;
        for (int e = 0; e < NE; ++e) { seg[e] = a; cur[e] = a; a += cnt[e]; }
        seg[NE] = a;
        int nt = 0;
        for (int e = 0; e < NE; ++e)
            for (int m0 = 0; m0 < cnt[e]; m0 += 64) d64[nt++] = (e << 16) | (m0 / 64);
        for (; nt < MAXT64; ++nt) d64[nt] = -1;
        nt = 0;
        for (int e = 0; e < NE; ++e)
            for (int m0 = 0; m0 < cnt[e]; m0 += 128) d128[nt++] = (e << 16) | (m0 / 128);
        for (; nt < MAXT128; ++nt) d128[nt] = -1;
    }
    __syncthreads();
    for (int s = tid; s < TSLOT; s += blockDim.x) {
        int e = ridx[s] & 7;
        int p = atomicAdd(&cur[e], 1);
        slot_of[p] = s;
        pos_of[s] = p;
    }
}

// ---------------- gather x rows into expert-sorted bf16 A ----------------
__global__ __launch_bounds__(256) void k_gather(const float* __restrict__ x,
                                                const int* __restrict__ slot_of,
                                                u16* __restrict__ A) {
    int r = blockIdx.x;
    int token = slot_of[r] >> 1;
    float4 v = ((const float4*)(x + (size_t)token * NH))[threadIdx.x];
    ushort4 o;
    o.x = f2bf(v.x); o.y = f2bf(v.y); o.z = f2bf(v.z); o.w = f2bf(v.w);
    ((ushort4*)(A + (size_t)r * NH))[threadIdx.x] = o;
}

// ---------------- transpose+convert: W[e][K][N] fp32 -> WT[e][N][K] bf16 ----------------
// LDS T stride 66 u16 (132B): odd half-stride -> consecutive n hit distinct banks.
// Writes: u32 k-pairs, <=2-way conflict. Reads: 4x b32 per 16B chunk, <=2-way.
__global__ __launch_bounds__(256) void k_tr(const float* __restrict__ W,
                                            u16* __restrict__ WT, int K, int N) {
    __shared__ u16 T[64][66];
    int tid = threadIdx.x;
    const float* in = W + (size_t)blockIdx.z * K * N;
    u16* out = WT + (size_t)blockIdx.z * N * K;
    int n0 = blockIdx.x * 64, k0 = blockIdx.y * 64;
#pragma unroll
    for (int p = 0; p < 2; ++p) {
        int kr = p * 32 + (tid >> 4) * 2;      // even k row
        int nc = (tid & 15) * 4;
        const float* r0 = in + (size_t)(k0 + kr) * N + n0 + nc;
        float4 v0 = *(const float4*)r0;
        float4 v1 = *(const float4*)(r0 + N);
#pragma unroll
        for (int i = 0; i < 4; ++i) {
            unsigned lo = f2bf(((const float*)&v0)[i]);
            unsigned hi = f2bf(((const float*)&v1)[i]);
            *(unsigned*)&T[nc + i][kr] = lo | (hi << 16);
        }
    }
    __syncthreads();
#pragma unroll
    for (int p = 0; p < 2; ++p) {
        int idx = p * 256 + tid;
        int nr = idx >> 3, kc = (idx & 7) * 8;
        unsigned q0 = *(const unsigned*)&T[nr][kc + 0];
        unsigned q1 = *(const unsigned*)&T[nr][kc + 2];
        unsigned q2 = *(const unsigned*)&T[nr][kc + 4];
        unsigned q3 = *(const unsigned*)&T[nr][kc + 6];
        uint4 vv = {q0, q1, q2, q3};
        *(uint4*)(out + (size_t)(n0 + nr) * K + k0 + kc) = vv;
    }
}

// ---------------- fast gate_up: 128x64 tile, all-DMA staging ----------------
__global__ __launch_bounds__(256) void k_gateup_f(
        const u16* __restrict__ A,       // [TSLOT][NH] bf16, expert-sorted
        const u16* __restrict__ wt,      // [NE][NGU][NH] bf16 (n-major)
        const float* __restrict__ bias,  // [NE][NGU]
        const int* __restrict__ seg, const int* __restrict__ desc,
        u16* __restrict__ inter) {       // [TSLOT][NI] bf16
    int d = desc[blockIdx.x];
    if (d < 0) return;
    int e = d >> 16, mt = d & 0xffff;
    int seg0 = seg[e], Te = seg[e + 1] - seg0, m0 = mt * 128;

    __shared__ __align__(16) u16 As[128 * 64];
    __shared__ __align__(16) u16 Bs[64 * 64];

    int tid = threadIdx.x;
    int lane = tid & 63, w = tid >> 6;
    int ml = lane & 15, kq = lane >> 4;
    int wm = w >> 1, wn = w & 1;
    int n0 = blockIdx.y * 64;
    const u16* wte = wt + (size_t)e * NGU * NH;
    int dr = lane >> 3, db = (lane & 7) ^ dr;

    f32x4 zero = {0.f, 0.f, 0.f, 0.f};
    f32x4 acc[4][2];
#pragma unroll
    for (int i = 0; i < 4; ++i) { acc[i][0] = zero; acc[i][1] = zero; }

    for (int kb = 0; kb < NH; kb += 64) {
        __syncthreads();
#pragma unroll
        for (int c = 0; c < 4; ++c) {
            int gr = seg0 + m0 + c * 32 + w * 8 + dr;
            if (gr > TSLOT - 1) gr = TSLOT - 1;          // clamp (pad-free ws)
            lds_dma16(A + (size_t)gr * NH + kb + db * 8, As + c * 2048 + w * 512);
        }
#pragma unroll
        for (int c = 0; c < 2; ++c) {
            int row = c * 32 + w * 8 + dr;
            lds_dma16(wte + (size_t)(n0 + row) * NH + kb + db * 8, Bs + c * 2048 + w * 512);
        }
        __syncthreads();

#pragma unroll
        for (int kk = 0; kk < 64; kk += 32) {
            s16x8 af[4], bf[2];
#pragma unroll
            for (int i = 0; i < 4; ++i)
                af[i] = *(const s16x8*)((char*)As + lds_off(wm * 64 + i * 16 + ml, (kk >> 3) + kq));
#pragma unroll
            for (int i = 0; i < 2; ++i)
                bf[i] = *(const s16x8*)((char*)Bs + lds_off(wn * 32 + i * 16 + ml, (kk >> 3) + kq));
#pragma unroll
            for (int mi = 0; mi < 4; ++mi)
#pragma unroll
                for (int ni = 0; ni < 2; ++ni)
                    acc[mi][ni] = __builtin_amdgcn_mfma_f32_16x16x32_bf16(
                        af[mi], bf[ni], acc[mi][ni], 0, 0, 0);
        }
    }

#pragma unroll
    for (int ni = 0; ni < 2; ++ni) {
        int n = n0 + wn * 32 + ni * 16 + ml;
        float bv = bias[e * NGU + n];
#pragma unroll
        for (int mi = 0; mi < 4; ++mi) {
#pragma unroll
            for (int r = 0; r < 4; ++r) {
                float v = acc[mi][ni][r] + bv;
                float pr = __shfl_xor(v, 1, 64);
                float g = (lane & 1) ? pr : v;
                float u = (lane & 1) ? v : pr;
                g = fminf(g, 7.0f);
                u = fminf(fmaxf(u, -7.0f), 7.0f);
                float glu = g / (1.0f + __expf(-1.702f * g));
                float y = (u + 1.0f) * glu;
                int mloc = wm * 64 + mi * 16 + kq * 4 + r;
                if (!(lane & 1) && (m0 + mloc) < Te)
                    inter[(size_t)(seg0 + m0 + mloc) * NI + (n >> 1)] = f2bf(y);
            }
        }
    }
}

// ---------------- fast down: 128x64 tile, split-K x2, plain fp32 stores ----------------
__global__ __launch_bounds__(256) void k_down_f(
        const u16* __restrict__ inter,   // [TSLOT][NI] bf16
        const u16* __restrict__ wt,      // [NE][NH][NI] bf16 (n-major)
        const float* __restrict__ bias,  // [NE][NH]
        const int* __restrict__ seg, const int* __restrict__ desc,
        float* __restrict__ dA,          // [TSLOT][NH] fp32 (kz=0 half, +bias)
        float* __restrict__ dB) {        // [TSLOT][NH] fp32 (kz=1 half)
    int d = desc[blockIdx.x];
    if (d < 0) return;
    int e = d >> 16, mt = d & 0xffff;
    int seg0 = seg[e], Te = seg[e + 1] - seg0, m0 = mt * 128;
    int kz = blockIdx.z;

    __shared__ __align__(16) u16 As[128 * 64];
    __shared__ __align__(16) u16 Bs[64 * 64];

    int tid = threadIdx.x;
    int lane = tid & 63, w = tid >> 6;
    int ml = lane & 15, kq = lane >> 4;
    int wm = w >> 1, wn = w & 1;
    int n0 = blockIdx.y * 64;
    const u16* wte = wt + (size_t)e * NH * NI;
    int dr = lane >> 3, db = (lane & 7) ^ dr;

    f32x4 zero = {0.f, 0.f, 0.f, 0.f};
    f32x4 acc[4][2];
#pragma unroll
    for (int i = 0; i < 4; ++i) { acc[i][0] = zero; acc[i][1] = zero; }

    int kbeg = kz * (NI / 2);
    for (int kb = kbeg; kb < kbeg + NI / 2; kb += 64) {
        __syncthreads();
#pragma unroll
        for (int c = 0; c < 4; ++c) {
            int gr = seg0 + m0 + c * 32 + w * 8 + dr;
            if (gr > TSLOT - 1) gr = TSLOT - 1;          // clamp (pad-free ws)
            lds_dma16(inter + (size_t)gr * NI + kb + db * 8, As + c * 2048 + w * 512);
        }
#pragma unroll
        for (int c = 0; c < 2; ++c) {
            int row = c * 32 + w * 8 + dr;
            lds_dma16(wte + (size_t)(n0 + row) * NI + kb + db * 8, Bs + c * 2048 + w * 512);
        }
        __syncthreads();

#pragma unroll
        for (int kk = 0; kk < 64; kk += 32) {
            s16x8 af[4], bf[2];
#pragma unroll
            for (int i = 0; i < 4; ++i)
                af[i] = *(const s16x8*)((char*)As + lds_off(wm * 64 + i * 16 + ml, (kk >> 3) + kq));
#pragma unroll
            for (int i = 0; i < 2; ++i)
                bf[i] = *(const s16x8*)((char*)Bs + lds_off(wn * 32 + i * 16 + ml, (kk >> 3) + kq));
#pragma unroll
            for (int mi = 0; mi < 4; ++mi)
#pragma unroll
                for (int ni = 0; ni < 2; ++ni)
                    acc[mi][ni] = __builtin_amdgcn_mfma_f32_16x16x32_bf16(
                        af[mi], bf[ni], acc[mi][ni], 0, 0, 0);
        }
    }

    float* dst = kz ? dB : dA;
    float bv[2];
#pragma unroll
    for (int ni = 0; ni < 2; ++ni)
        bv[ni] = (kz == 0) ? bias[e * NH + n0 + wn * 32 + ni * 16 + ml] : 0.0f;

#pragma unroll
    for (int mi = 0; mi < 4; ++mi) {
#pragma unroll
        for (int r = 0; r < 4; ++r) {
            int mloc = wm * 64 + mi * 16 + kq * 4 + r;
            if ((m0 + mloc) < Te) {
                size_t row = (size_t)(seg0 + m0 + mloc);
#pragma unroll
                for (int ni = 0; ni < 2; ++ni) {
                    int n = n0 + wn * 32 + ni * 16 + ml;
                    dst[row * NH + n] = acc[mi][ni][r] + bv[ni];
                }
            }
        }
    }
}

// ---------------- combine: out[t] = sum_k rw[t][e_k] * (dA[row_k] + dB[row_k]) ----------------
__global__ __launch_bounds__(256) void k_comb(
        const float* __restrict__ dA, const float* __restrict__ dB,
        const float* __restrict__ rw, const int* __restrict__ ridx,
        const int* __restrict__ pos_of, float* __restrict__ out) {
    int t = blockIdx.x;
    int h = threadIdx.x * 4;
    float4 s = {0.f, 0.f, 0.f, 0.f};
#pragma unroll
    for (int k = 0; k < 2; ++k) {
        int slot = t * 2 + k;
        int e = ridx[slot] & 7;
        float wgt = rw[t * NE + e];
        size_t r = (size_t)pos_of[slot];
        float4 a = *(const float4*)(dA + r * NH + h);
        float4 b = *(const float4*)(dB + r * NH + h);
        s.x += wgt * (a.x + b.x);
        s.y += wgt * (a.y + b.y);
        s.z += wgt * (a.z + b.z);
        s.w += wgt * (a.w + b.w);
    }
    *(float4*)(out + (size_t)t * NH + h) = s;
}

// ---------------- slow-path kernels (round-2, proven) ----------------
__global__ __launch_bounds__(256) void k_gateup_s(
        const float* __restrict__ x, const float* __restrict__ w,
        const float* __restrict__ bias,
        const int* __restrict__ seg, const int* __restrict__ desc,
        const int* __restrict__ slot_of, u16* __restrict__ inter) {
    int d = desc[blockIdx.x];
    if (d < 0) return;
    int e = d >> 16, mt = d & 0xffff;
    int seg0 = seg[e], Te = seg[e + 1] - seg0, m0 = mt * 64;
    __shared__ u16 As[64 * 40];
    __shared__ int tok[64];
    int tid = threadIdx.x;
    if (tid < 64) {
        int m = m0 + tid;
        tok[tid] = (m < Te) ? (slot_of[seg0 + m] >> 1) : -1;
    }
    __syncthreads();
    int lane = tid & 63, wave = tid >> 6;
    int arow = tid >> 2, acol = (tid & 3) * 8;
    int ta = tok[arow];
    int kq = lane >> 4, ml = lane & 15;
    int nb = blockIdx.y * 128 + wave * 32;
    const float* wp = w + (size_t)e * NH * NGU;
    f32x4 zero = {0.f, 0.f, 0.f, 0.f};
    f32x4 acc[4][2];
#pragma unroll
    for (int i = 0; i < 4; ++i) { acc[i][0] = zero; acc[i][1] = zero; }
    for (int kb = 0; kb < NH; kb += 32) {
        float4 a0 = {0, 0, 0, 0}, a1 = {0, 0, 0, 0};
        if (ta >= 0) {
            const float* xp = x + (size_t)ta * NH + kb + acol;
            a0 = *(const float4*)xp; a1 = *(const float4*)(xp + 4);
        }
        s16x8 av;
        av[0] = (short)f2bf(a0.x); av[1] = (short)f2bf(a0.y);
        av[2] = (short)f2bf(a0.z); av[3] = (short)f2bf(a0.w);
        av[4] = (short)f2bf(a1.x); av[5] = (short)f2bf(a1.y);
        av[6] = (short)f2bf(a1.z); av[7] = (short)f2bf(a1.w);
        __syncthreads();
        *(s16x8*)&As[arow * 40 + acol] = av;
        __syncthreads();
        s16x8 afr[4];
#pragma unroll
        for (int msi = 0; msi < 4; ++msi)
            afr[msi] = *(const s16x8*)&As[(msi * 16 + ml) * 40 + kq * 8];
        s16x8 bfr[2];
#pragma unroll
        for (int s = 0; s < 2; ++s) {
            const float* bp = wp + (size_t)(kb + kq * 8) * NGU + nb + s * 16 + ml;
#pragma unroll
            for (int j = 0; j < 8; ++j) bfr[s][j] = (short)f2bf(bp[(size_t)j * NGU]);
        }
#pragma unroll
        for (int msi = 0; msi < 4; ++msi)
#pragma unroll
            for (int s = 0; s < 2; ++s)
                acc[msi][s] = __builtin_amdgcn_mfma_f32_16x16x32_bf16(
                    afr[msi], bfr[s], acc[msi][s], 0, 0, 0);
    }
#pragma unroll
    for (int s = 0; s < 2; ++s) {
        int n = nb + s * 16 + ml;
        float bv = bias[e * NGU + n];
#pragma unroll
        for (int msi = 0; msi < 4; ++msi) {
#pragma unroll
            for (int r = 0; r < 4; ++r) {
                float v = acc[msi][s][r] + bv;
                float pr = __shfl_xor(v, 1, 64);
                float g = (lane & 1) ? pr : v;
                float u = (lane & 1) ? v : pr;
                g = fminf(g, 7.0f);
                u = fminf(fmaxf(u, -7.0f), 7.0f);
                float glu = g / (1.0f + __expf(-1.702f * g));
                float y = (u + 1.0f) * glu;
                int mrow = m0 + msi * 16 + kq * 4 + r;
                if (!(lane & 1) && mrow < Te)
                    inter[(size_t)(seg0 + mrow) * NI + (n >> 1)] = f2bf(y);
            }
        }
    }
}

__global__ __launch_bounds__(256) void k_down_s(
        const u16* __restrict__ inter, const float* __restrict__ w,
        const float* __restrict__ bias, const float* __restrict__ rw,
        const int* __restrict__ seg, const int* __restrict__ desc,
        const int* __restrict__ slot_of, float* __restrict__ out) {
    int d = desc[blockIdx.x];
    if (d < 0) return;
    int e = d >> 16, mt = d & 0xffff;
    int seg0 = seg[e], Te = seg[e + 1] - seg0, m0 = mt * 64;
    __shared__ u16 As[64 * 40];
    int tid = threadIdx.x;
    int lane = tid & 63, wave = tid >> 6;
    int arow = tid >> 2, acol = (tid & 3) * 8;
    bool avalid = (m0 + arow) < Te;
    int kq = lane >> 4, ml = lane & 15;
    int nb = blockIdx.y * 128 + wave * 32;
    const float* wp = w + (size_t)e * NI * NH;
    f32x4 zero = {0.f, 0.f, 0.f, 0.f};
    f32x4 acc[4][2];
#pragma unroll
    for (int i = 0; i < 4; ++i) { acc[i][0] = zero; acc[i][1] = zero; }
    for (int kb = 0; kb < NI; kb += 32) {
        s16x8 av = {0, 0, 0, 0, 0, 0, 0, 0};
        if (avalid) av = *(const s16x8*)(inter + (size_t)(seg0 + m0 + arow) * NI + kb + acol);
        __syncthreads();
        *(s16x8*)&As[arow * 40 + acol] = av;
        __syncthreads();
        s16x8 afr[4];
#pragma unroll
        for (int msi = 0; msi < 4; ++msi)
            afr[msi] = *(const s16x8*)&As[(msi * 16 + ml) * 40 + kq * 8];
        s16x8 bfr[2];
#pragma unroll
        for (int s = 0; s < 2; ++s) {
            const float* bp = wp + (size_t)(kb + kq * 8) * NH + nb + s * 16 + ml;
#pragma unroll
            for (int j = 0; j < 8; ++j) bfr[s][j] = (short)f2bf(bp[(size_t)j * NH]);
        }
#pragma unroll
        for (int msi = 0; msi < 4; ++msi)
#pragma unroll
            for (int s = 0; s < 2; ++s)
                acc[msi][s] = __builtin_amdgcn_mfma_f32_16x16x32_bf16(
                    afr[msi], bfr[s], acc[msi][s], 0, 0, 0);
    }
    float bv[2];
    bv[0] = bias[e * NH + nb + ml];
    bv[1] = bias[e * NH + nb + 16 + ml];
#pragma unroll
    for (int msi = 0; msi < 4; ++msi) {
#pragma unroll
        for (int r = 0; r < 4; ++r) {
            int mrow = m0 + msi * 16 + kq * 4 + r;
            if (mrow < Te) {
                int slot = slot_of[seg0 + mrow];
                int token = slot >> 1;
                float wgt = rw[token * NE + e];
#pragma unroll
                for (int s = 0; s < 2; ++s) {
                    int n = nb + s * 16 + ml;
                    atomicAdd(&out[(size_t)token * NH + n], (acc[msi][s][r] + bv[s]) * wgt);
                }
            }
        }
    }
}

extern "C" void kernel_launch(void* const* d_in, const int* in_sizes, int n_in,
                              void* d_out, int out_size, void* d_ws, size_t ws_size,
                              hipStream_t stream) {
    const float* x   = (const float*)d_in[0];
    const int*   ri  = (const int*)d_in[1];
    const float* rw  = (const float*)d_in[2];
    const float* wgu = (const float*)d_in[3];
    const float* bgu = (const float*)d_in[4];
    const float* wd  = (const float*)d_in[5];
    const float* bd  = (const float*)d_in[6];
    float* out = (float*)d_out;

    char* ws = (char*)d_ws;
    int* seg     = (int*)(ws + WS_SEG);
    int* d64     = (int*)(ws + WS_DESC64);
    int* d128    = (int*)(ws + WS_DESC128);
    int* slot_of = (int*)(ws + WS_SLOT);
    int* pos_of  = (int*)(ws + WS_POS);
    u16* inter   = (u16*)(ws + WS_INTER);

    hipLaunchKernelGGL(k_build, dim3(1), dim3(256), 0, stream, ri, seg, d64, d128,
                       slot_of, pos_of);

    if (ws_size >= WS_NEED_FAST) {
        u16*   aReg = (u16*)(ws + WS_AREG);                 // A_sorted, then dA
        float* dA   = (float*)(ws + WS_AREG);
        u16*   wReg = (u16*)(ws + WS_WREG);                 // WT_gu, then WT_d + dB
        float* dB   = (float*)(ws + WS_WREG + WS_DB_OFF);

        hipLaunchKernelGGL(k_tr, dim3(NGU / 64, NH / 64, NE), dim3(256), 0, stream,
                           wgu, wReg, NH, NGU);
        hipLaunchKernelGGL(k_gather, dim3(TSLOT), dim3(256), 0, stream, x, slot_of, aReg);
        hipLaunchKernelGGL(k_gateup_f, dim3(MAXT128, NGU / 64), dim3(256), 0, stream,
                           aReg, wReg, bgu, seg, d128, inter);
        hipLaunchKernelGGL(k_tr, dim3(NH / 64, NI / 64, NE), dim3(256), 0, stream,
                           wd, wReg, NI, NH);
        hipLaunchKernelGGL(k_down_f, dim3(MAXT128, NH / 64, 2), dim3(256), 0, stream,
                           inter, wReg, bd, seg, d128, dA, dB);
        hipLaunchKernelGGL(k_comb, dim3(MTOK), dim3(256), 0, stream,
                           dA, dB, rw, ri, pos_of, out);
    } else {
        hipMemsetAsync(out, 0, (size_t)MTOK * NH * sizeof(float), stream);
        hipLaunchKernelGGL(k_gateup_s, dim3(MAXT64, NGU / 128), dim3(256), 0, stream,
                           x, wgu, bgu, seg, d64, slot_of, inter);
        hipLaunchKernelGGL(k_down_s, dim3(MAXT64, NH / 128), dim3(256), 0, stream,
                           inter, wd, bd, rw, seg, d64, slot_of, out);
    }
}